// Round 2
// baseline (872.668 us; speedup 1.0000x reference)
//
#include <hip/hip_runtime.h>

#define CRF_B 256
#define CRF_S 1024
#define CRF_T 128

typedef __attribute__((ext_vector_type(4))) float f32x4;

// Workgroup barrier that waits only for LDS ops (lgkmcnt), NOT vmcnt.
// __syncthreads() drains vmcnt(0) which would kill our global prefetch
// distance every step. LDS producer->consumer only needs lgkmcnt(0).
__device__ __forceinline__ void barrier_lds_only() {
    __asm__ volatile("s_waitcnt lgkmcnt(0)\n\ts_barrier" ::: "memory");
}

// ---------------------------------------------------------------------------
// Kernel 1: tag-gather terms of the gold score, negated into out.
// ---------------------------------------------------------------------------
__global__ __launch_bounds__(256) void crf_gold_kernel(
    const float* __restrict__ em, const int* __restrict__ tags,
    const float* __restrict__ mask, const float* __restrict__ startT,
    const float* __restrict__ endT, const float* __restrict__ trans,
    float* __restrict__ out)
{
    const int b = blockIdx.x;
    const int tid = threadIdx.x;
    const int* tg = tags + (size_t)b * CRF_S;
    const float* mk = mask + (size_t)b * CRF_S;
    float acc = 0.f;
#pragma unroll
    for (int k = 0; k < 4; ++k) {
        int t = tid + k * 256;
        int tagt = tg[t];
        float m = mk[t];
        acc += em[((size_t)b * CRF_S + t) * CRF_T + tagt] * m;
        if (t >= 1) acc += trans[tg[t - 1] * CRF_T + tagt] * m;
    }
    if (tid == 0) {
        acc += startT[tg[0]];
        acc += endT[tg[CRF_S - 1]] * mk[CRF_S - 1];
    }
#pragma unroll
    for (int d = 1; d < 64; d <<= 1) acc += __shfl_xor(acc, d);
    __shared__ float r4[4];
    if ((tid & 63) == 0) r4[tid >> 6] = acc;
    __syncthreads();
    if (tid == 0) {
        float tot = (r4[0] + r4[1]) + (r4[2] + r4[3]);
        atomicAdd(out, -tot * (1.0f / CRF_B));
    }
}

// ---------------------------------------------------------------------------
// Kernel 2: scaled linear-domain forward recursion + fused log-softmax
// denominator. One block per batch, 256 threads (4 waves).
//
// Thread mapping: j = tid>>1 (one full column), h = tid&1 (row half).
// E = exp(trans[h*64 .. h*64+63][j]) in 64 VGPRs. Dot product:
// 64 FMAs (as v_pk_fma_f32 via f32x4 elementwise fma) + ONE shfl_xor(,1)
// (DPP). One lgkm-only barrier per step; c/esum reductions pipelined one
// step late; emissions+mask register-prefetched 4-8 steps ahead (never
// drained, thanks to barrier_lds_only).
// ---------------------------------------------------------------------------
__global__ __launch_bounds__(256) void crf_fwd_kernel(
    const float* __restrict__ em, const float* __restrict__ mask,
    const float* __restrict__ startT, const float* __restrict__ endT,
    const float* __restrict__ trans, float* __restrict__ out)
{
    const int b = blockIdx.x;
    const int tid = threadIdx.x;
    const int w = tid >> 6;
    const int l = tid & 63;
    const int j = tid >> 1;   // column 0..127
    const int h = tid & 1;    // row half 0/1

    __shared__ float Abuf[2][CRF_T];
    __shared__ float2 parts[2][4];   // per-wave (csum, esum)
    __shared__ float red[8];

    // E tile: 64 rows of column j (rows h*64 .. h*64+63). Global loads are
    // two 128B segments per instruction across the wave (coalesced enough;
    // trans is 64 KB, L2/L3 resident).
    f32x4 E4[16];
    {
        float* Ef = (float*)E4;
#pragma unroll
        for (int r = 0; r < 64; ++r)
            Ef[r] = __expf(trans[(h * 64 + r) * CRF_T + j]);
    }

    const float* emb = em + (size_t)b * CRF_S * CRF_T + j;
    const float* mkb = mask + (size_t)b * CRF_S;

    float logZ = 0.f;     // sum log c_t, t = 0..S-2
    float S2 = 0.f;       // sum_t log(sum_j exp(em_tj)) * m_t
    float m_prev = 1.f;   // mask[t-1], consumed one step late

    float eA[4], eB[4], mA[4], mB[4];
#pragma unroll
    for (int k = 0; k < 4; ++k) { eA[k] = emb[(size_t)k * CRF_T]; mA[k] = mkb[k]; }

    auto STEP = [&](int t, float emval, float mval) {
        const int rb = (t & 1) ^ 1;  // buffer written at t-1
        const int wb = t & 1;
        float rc = 1.f;
        if (t > 0) {
            // pipelined: consume last step's scale + esum reductions
            const float4* p4 = (const float4*)&parts[rb][0];
            float4 pa = p4[0], pb = p4[1];
            float c  = (pa.x + pa.z) + (pb.x + pb.z);
            float es = (pa.y + pa.w) + (pb.y + pb.w);
            rc = __builtin_amdgcn_rcpf(c);
            logZ += __logf(c);
            S2 += __logf(es) * m_prev;
        }

        float d;
        if (t > 0) {
            const f32x4* A4 = (const f32x4*)&Abuf[rb][h * 64];
            f32x4 ac0 = {0.f, 0.f, 0.f, 0.f}, ac1 = ac0, ac2 = ac0, ac3 = ac0;
#pragma unroll
            for (int i = 0; i < 16; i += 4) {
                ac0 = __builtin_elementwise_fma(A4[i + 0], E4[i + 0], ac0);
                ac1 = __builtin_elementwise_fma(A4[i + 1], E4[i + 1], ac1);
                ac2 = __builtin_elementwise_fma(A4[i + 2], E4[i + 2], ac2);
                ac3 = __builtin_elementwise_fma(A4[i + 3], E4[i + 3], ac3);
            }
            f32x4 s = (ac0 + ac1) + (ac2 + ac3);
            float dh = (s.x + s.y) + (s.z + s.w);
            d = dh + __shfl_xor(dh, 1);          // combine the two row halves
        } else {
            d = __expf(startT[j]);               // alpha0 = start + em0
        }

        float e = __expf(emval);
        float a = e * rc * d;
        if (h == 0) Abuf[wb][j] = a;

        // per-wave reductions of csum/esum over the 32 distinct j's
        // (values are pair-duplicated; reduce over xor in {2,4,8,16,32})
        float cs = a, eo = e;
#pragma unroll
        for (int dd = 2; dd <= 32; dd <<= 1) {
            cs += __shfl_xor(cs, dd);
            eo += __shfl_xor(eo, dd);
        }
        if (l == 0) parts[wb][w] = make_float2(cs, eo);
        m_prev = mval;
        barrier_lds_only();
    };

    for (int c2 = 0; c2 < 128; ++c2) {
        const int t0 = c2 * 8;
#pragma unroll
        for (int k = 0; k < 4; ++k) {
            eB[k] = emb[(size_t)(t0 + 4 + k) * CRF_T];
            mB[k] = mkb[t0 + 4 + k];
        }
#pragma unroll
        for (int k = 0; k < 4; ++k) STEP(t0 + k, eA[k], mA[k]);
        if (c2 < 127) {
#pragma unroll
            for (int k = 0; k < 4; ++k) {
                eA[k] = emb[(size_t)(t0 + 8 + k) * CRF_T];
                mA[k] = mkb[t0 + 8 + k];
            }
        }
#pragma unroll
        for (int k = 0; k < 4; ++k) STEP(t0 + 4 + k, eB[k], mB[k]);
    }

    // ---- finale: A~_{S-1} in Abuf[1], (c,esum)_{S-1} in parts[1] ----
    const float mlast = mkb[CRF_S - 1];
    {
        const float4* p4 = (const float4*)&parts[1][0];
        float4 pa = p4[0], pb = p4[1];
        float es = (pa.y + pa.w) + (pb.y + pb.w);
        S2 += __logf(es) * mlast;
        // c_{S-1} intentionally NOT in logZ (never used as a normalizer)
    }
    float v = -3.0e38f;
    if (tid < 128)
        v = (__logf(Abuf[1][tid]) + logZ) * mlast + endT[tid];
    float mx = v;
#pragma unroll
    for (int dd = 1; dd < 64; dd <<= 1) mx = fmaxf(mx, __shfl_xor(mx, dd));
    if (l == 0) red[w] = mx;
    __syncthreads();
    mx = fmaxf(fmaxf(red[0], red[1]), fmaxf(red[2], red[3]));
    float ex = (tid < 128) ? __expf(v - mx) : 0.f;
#pragma unroll
    for (int dd = 1; dd < 64; dd <<= 1) ex += __shfl_xor(ex, dd);
    if (l == 0) red[4 + w] = ex;
    __syncthreads();
    if (tid == 0) {
        float sm = (red[4] + red[5]) + (red[6] + red[7]);
        float fwd = mx + __logf(sm);
        atomicAdd(out, (fwd + S2) * (1.0f / CRF_B));
    }
}

// ---------------------------------------------------------------------------
extern "C" void kernel_launch(void* const* d_in, const int* in_sizes, int n_in,
                              void* d_out, int out_size, void* d_ws, size_t ws_size,
                              hipStream_t stream)
{
    const float* em     = (const float*)d_in[0];
    const int*   tags   = (const int*)d_in[1];
    const float* mask   = (const float*)d_in[2];
    const float* startT = (const float*)d_in[3];
    const float* endT   = (const float*)d_in[4];
    const float* trans  = (const float*)d_in[5];
    float* out = (float*)d_out;

    hipMemsetAsync(out, 0, sizeof(float), stream);
    hipLaunchKernelGGL(crf_gold_kernel, dim3(CRF_B), dim3(256), 0, stream,
                       em, tags, mask, startT, endT, trans, out);
    hipLaunchKernelGGL(crf_fwd_kernel, dim3(CRF_B), dim3(256), 0, stream,
                       em, mask, startT, endT, trans, out);
}

// Round 3
// 730.096 us; speedup vs baseline: 1.1953x; 1.1953x over previous
//
#include <hip/hip_runtime.h>

#define CRF_B 256
#define CRF_S 1024
#define CRF_T 128

typedef __attribute__((ext_vector_type(2))) float f32x2;
typedef __attribute__((ext_vector_type(4))) float f32x4;

// Workgroup barrier that waits only for LDS ops (lgkmcnt), NOT vmcnt:
// __syncthreads() drains vmcnt(0), which would serialize our global em/mask
// prefetches into the per-step critical path. LDS producer->consumer
// correctness only needs lgkmcnt(0) + s_barrier.
__device__ __forceinline__ void barrier_lds_only() {
    __asm__ volatile("s_waitcnt lgkmcnt(0)\n\ts_barrier" ::: "memory");
}

__device__ __forceinline__ f32x2 fma2(float a, f32x2 e, f32x2 acc) {
    f32x2 aa = {a, a};
    return __builtin_elementwise_fma(aa, e, acc);
}

// ---------------------------------------------------------------------------
// Kernel 1: tag-gather terms of the gold score, negated into out.
// ---------------------------------------------------------------------------
__global__ __launch_bounds__(256) void crf_gold_kernel(
    const float* __restrict__ em, const int* __restrict__ tags,
    const float* __restrict__ mask, const float* __restrict__ startT,
    const float* __restrict__ endT, const float* __restrict__ trans,
    float* __restrict__ out)
{
    const int b = blockIdx.x;
    const int tid = threadIdx.x;
    const int* tg = tags + (size_t)b * CRF_S;
    const float* mk = mask + (size_t)b * CRF_S;
    float acc = 0.f;
#pragma unroll
    for (int k = 0; k < 4; ++k) {
        int t = tid + k * 256;
        int tagt = tg[t];
        float m = mk[t];
        acc += em[((size_t)b * CRF_S + t) * CRF_T + tagt] * m;
        if (t >= 1) acc += trans[tg[t - 1] * CRF_T + tagt] * m;
    }
    if (tid == 0) {
        acc += startT[tg[0]];
        acc += endT[tg[CRF_S - 1]] * mk[CRF_S - 1];
    }
#pragma unroll
    for (int d = 1; d < 64; d <<= 1) acc += __shfl_xor(acc, d);
    __shared__ float r4[4];
    if ((tid & 63) == 0) r4[tid >> 6] = acc;
    __syncthreads();
    if (tid == 0) {
        float tot = (r4[0] + r4[1]) + (r4[2] + r4[3]);
        atomicAdd(out, -tot * (1.0f / CRF_B));
    }
}

// ---------------------------------------------------------------------------
// Kernel 2: scaled linear-domain forward recursion, lazy (every-4-step)
// rescaling with a 2-step-stale normalizer, fused log-softmax-denominator
// sum via an off-critical-path LDS ring. One block per batch, 256 threads.
//
// Thread mapping: w=tid>>6, l=tid&63, cg=l&15 (column-pair), r=l>>4 (row
// group of 32). Columns j0=(w*16+cg)*2, j0+1. E=exp(trans) tile: 32 rows x
// 2 cols in 64 VGPRs, k-swizzled so the per-step 8x ds_read_b128 of A hits
// disjoint bank quads across the 4 r-groups (16-lane broadcast per address).
// ---------------------------------------------------------------------------
__global__ __launch_bounds__(256) void crf_fwd_kernel(
    const float* __restrict__ em, const float* __restrict__ mask,
    const float* __restrict__ startT, const float* __restrict__ endT,
    const float* __restrict__ trans, float* __restrict__ out)
{
    const int b = blockIdx.x;
    const int tid = threadIdx.x;
    const int w = tid >> 6;
    const int l = tid & 63;
    const int cg = l & 15;
    const int r = l >> 4;
    const int j0 = (w * 16 + cg) * 2;

    __shared__ __align__(16) float Abuf[2][CRF_T];
    __shared__ __align__(16) float partsA[16];      // csum partials (t%4==2)
    __shared__ __align__(16) float partsE[16][16];  // esum partials ring
    __shared__ float red[12];

    // byte offsets of the 8 swizzled b128 reads (per-thread constant)
    int off[8];
#pragma unroll
    for (int k = 0; k < 8; ++k) off[k] = 16 * ((k + r) & 7);

    // E tile, stored in read-swizzled order: E2[4k+s] = exp row 32r+4*((k+r)&7)+s
    f32x2 E2[32];
#pragma unroll
    for (int k = 0; k < 8; ++k) {
        const int kp = (k + r) & 7;
#pragma unroll
        for (int s = 0; s < 4; ++s) {
            const int i = r * 32 + kp * 4 + s;
            float2 t2 = *(const float2*)&trans[i * CRF_T + j0];
            E2[4 * k + s].x = __expf(t2.x);
            E2[4 * k + s].y = __expf(t2.y);
        }
    }

    const float* emb = em + (size_t)b * CRF_S * CRF_T + j0;
    const float* mkb = mask + (size_t)b * CRF_S;

    float logZ = 0.f;   // sum of logs of applied rescale factors
    float S2 = 0.f;     // partial sum of log(sum_j exp(em_tj)) * m_t (8 threads)

    auto STEP = [&](int t, bool first, float2 emv) {
        const int rb = (t & 1) ^ 1;
        const int wb = t & 1;
        float e0 = __expf(emv.x), e1 = __expf(emv.y);

        // esum partial: 2 shfl rounds over cg bits {0,1}; ring write (off-path)
        float eo = e0 + e1;
        eo += __shfl_xor(eo, 1);
        eo += __shfl_xor(eo, 2);
        if (r == 0 && (cg & 3) == 0) partsE[t & 15][w * 4 + (cg >> 2)] = eo;

        // lazy rescale factor (from csum written at t-2), every 4th step
        const bool resc = ((t & 3) == 0) && !first;
        float rc = 1.f;
        if (resc) {
            const f32x4* pa = (const f32x4*)partsA;
            f32x4 s = (pa[0] + pa[1]) + (pa[2] + pa[3]);
            float c = (s.x + s.y) + (s.z + s.w);
            rc = __builtin_amdgcn_rcpf(c);
            logZ += __logf(c);
        }

        float d0, d1;
        if (!first) {
            f32x2 ac0 = {0.f, 0.f}, ac1 = ac0, ac2 = ac0, ac3 = ac0;
            const char* Ab = (const char*)&Abuf[rb][r * 32];
#pragma unroll
            for (int k = 0; k < 8; ++k) {
                f32x4 av = *(const f32x4*)(Ab + off[k]);
                ac0 = fma2(av.x, E2[4 * k + 0], ac0);
                ac1 = fma2(av.y, E2[4 * k + 1], ac1);
                ac2 = fma2(av.z, E2[4 * k + 2], ac2);
                ac3 = fma2(av.w, E2[4 * k + 3], ac3);
            }
            f32x2 dd = (ac0 + ac1) + (ac2 + ac3);
            float p0 = dd.x, p1 = dd.y;
            // reduce the 4 row-group partials: xor over l bits 4,5
            p0 += __shfl_xor(p0, 16); p1 += __shfl_xor(p1, 16);
            p0 += __shfl_xor(p0, 32); p1 += __shfl_xor(p1, 32);
            d0 = p0; d1 = p1;
        } else {
            float2 s2v = *(const float2*)&startT[j0];
            d0 = __expf(s2v.x); d1 = __expf(s2v.y);
        }

        float a0 = e0 * d0, a1 = e1 * d1;
        if (resc) { a0 *= rc; a1 *= rc; }
        if (r == 0) *(float2*)&Abuf[wb][j0] = make_float2(a0, a1);

        if ((t & 3) == 2) {  // csum partial for the rescale 2 steps later
            float cs = a0 + a1;
            cs += __shfl_xor(cs, 1);
            cs += __shfl_xor(cs, 2);
            if (r == 0 && (cg & 3) == 0) partsA[w * 4 + (cg >> 2)] = cs;
        }
        barrier_lds_only();
    };

    float2 eA[4], eB[4];
#pragma unroll
    for (int k = 0; k < 4; ++k) eA[k] = *(const float2*)(emb + (size_t)k * CRF_T);

    // ---- chunk 0 (peeled: t=0 special) ----
    {
#pragma unroll
        for (int k = 0; k < 4; ++k) eB[k] = *(const float2*)(emb + (size_t)(4 + k) * CRF_T);
        STEP(0, true, eA[0]);
        STEP(1, false, eA[1]);
        STEP(2, false, eA[2]);
        STEP(3, false, eA[3]);
#pragma unroll
        for (int k = 0; k < 4; ++k) eA[k] = *(const float2*)(emb + (size_t)(8 + k) * CRF_T);
        STEP(4, false, eB[0]);
        STEP(5, false, eB[1]);
        STEP(6, false, eB[2]);
        STEP(7, false, eB[3]);
    }

    for (int c2 = 1; c2 < 128; ++c2) {
        const int t0 = c2 * 8;
        // esum ring consumer: 8 threads handle steps t0-8 .. t0-1 (off-path)
        if ((tid & 31) == 0) {
            const int te = t0 - 8 + (tid >> 5);
            const f32x4* pe = (const f32x4*)partsE[te & 15];
            f32x4 s = (pe[0] + pe[1]) + (pe[2] + pe[3]);
            float es = (s.x + s.y) + (s.z + s.w);
            S2 += __logf(es) * mkb[te];
        }
#pragma unroll
        for (int k = 0; k < 4; ++k) eB[k] = *(const float2*)(emb + (size_t)(t0 + 4 + k) * CRF_T);
        STEP(t0 + 0, false, eA[0]);
        STEP(t0 + 1, false, eA[1]);
        STEP(t0 + 2, false, eA[2]);
        STEP(t0 + 3, false, eA[3]);
        if (c2 < 127) {
#pragma unroll
            for (int k = 0; k < 4; ++k) eA[k] = *(const float2*)(emb + (size_t)(t0 + 8 + k) * CRF_T);
        }
        STEP(t0 + 4, false, eB[0]);
        STEP(t0 + 5, false, eB[1]);
        STEP(t0 + 6, false, eB[2]);
        STEP(t0 + 7, false, eB[3]);
    }

    // ---- drain esum ring for steps 1016..1023 ----
    if ((tid & 31) == 0) {
        const int te = 1016 + (tid >> 5);
        const f32x4* pe = (const f32x4*)partsE[te & 15];
        f32x4 s = (pe[0] + pe[1]) + (pe[2] + pe[3]);
        float es = (s.x + s.y) + (s.z + s.w);
        S2 += __logf(es) * mkb[te];
    }

    // ---- block-reduce S2 ----
    float s2p = S2;
#pragma unroll
    for (int dd = 1; dd < 64; dd <<= 1) s2p += __shfl_xor(s2p, dd);
    if (l == 0) red[8 + w] = s2p;

    // ---- final LSE over log(A~_{S-1}) + logZ + end ----
    const float mlast = mkb[CRF_S - 1];
    float v = -3.0e38f;
    if (tid < 128)
        v = (__logf(Abuf[1][tid]) + logZ) * mlast + endT[tid];
    float mx = v;
#pragma unroll
    for (int dd = 1; dd < 64; dd <<= 1) mx = fmaxf(mx, __shfl_xor(mx, dd));
    if (l == 0) red[w] = mx;
    __syncthreads();
    mx = fmaxf(fmaxf(red[0], red[1]), fmaxf(red[2], red[3]));
    float ex = (tid < 128) ? __expf(v - mx) : 0.f;
#pragma unroll
    for (int dd = 1; dd < 64; dd <<= 1) ex += __shfl_xor(ex, dd);
    if (l == 0) red[4 + w] = ex;
    __syncthreads();
    if (tid == 0) {
        float sm = (red[4] + red[5]) + (red[6] + red[7]);
        float fwd = mx + __logf(sm);
        float S2tot = (red[8] + red[9]) + (red[10] + red[11]);
        atomicAdd(out, (fwd + S2tot) * (1.0f / CRF_B));
    }
}

// ---------------------------------------------------------------------------
extern "C" void kernel_launch(void* const* d_in, const int* in_sizes, int n_in,
                              void* d_out, int out_size, void* d_ws, size_t ws_size,
                              hipStream_t stream)
{
    const float* em     = (const float*)d_in[0];
    const int*   tags   = (const int*)d_in[1];
    const float* mask   = (const float*)d_in[2];
    const float* startT = (const float*)d_in[3];
    const float* endT   = (const float*)d_in[4];
    const float* trans  = (const float*)d_in[5];
    float* out = (float*)d_out;

    hipMemsetAsync(out, 0, sizeof(float), stream);
    hipLaunchKernelGGL(crf_gold_kernel, dim3(CRF_B), dim3(256), 0, stream,
                       em, tags, mask, startT, endT, trans, out);
    hipLaunchKernelGGL(crf_fwd_kernel, dim3(CRF_B), dim3(256), 0, stream,
                       em, mask, startT, endT, trans, out);
}

// Round 4
// 635.365 us; speedup vs baseline: 1.3735x; 1.1491x over previous
//
#include <hip/hip_runtime.h>

#define CRF_B 256
#define CRF_S 1024
#define CRF_T 128

typedef __attribute__((ext_vector_type(4))) float f32x4;

// Barrier that waits only on LDS ops (lgkmcnt), NOT vmcnt: keeps global
// em-prefetch loads in flight across steps (__syncthreads drains vmcnt(0)).
__device__ __forceinline__ void barrier_lds_only() {
    __asm__ volatile("s_waitcnt lgkmcnt(0)\n\ts_barrier" ::: "memory");
}

// Quad-lane butterfly adds via DPP quad_perm (VALU pipe, no LDS/bpermute).
__device__ __forceinline__ float dpp_add_xor1(float x) {
    int y = __builtin_amdgcn_mov_dpp(__float_as_int(x), 0xB1, 0xF, 0xF, false);
    return x + __int_as_float(y);
}
__device__ __forceinline__ float dpp_add_xor2(float x) {
    int y = __builtin_amdgcn_mov_dpp(__float_as_int(x), 0x4E, 0xF, 0xF, false);
    return x + __int_as_float(y);
}

__device__ __forceinline__ f32x4 exp4(f32x4 v) {
    f32x4 r;
    r.x = __expf(v.x); r.y = __expf(v.y); r.z = __expf(v.z); r.w = __expf(v.w);
    return r;
}
__device__ __forceinline__ float hsum4(f32x4 v) {
    return (v.x + v.y) + (v.z + v.w);
}

// ---------------------------------------------------------------------------
// Kernel 1: tag-gather terms (negated) + S2 = sum_t m_t*log(sum_j exp(em_tj)).
// S2 is recursion-independent, so it lives here (parallel, HBM-bound),
// keeping the serial fwd kernel's critical path free of it.
// ---------------------------------------------------------------------------
__global__ __launch_bounds__(256) void crf_gold_kernel(
    const float* __restrict__ em, const int* __restrict__ tags,
    const float* __restrict__ mask, const float* __restrict__ startT,
    const float* __restrict__ endT, const float* __restrict__ trans,
    float* __restrict__ out)
{
    const int b = blockIdx.x;
    const int tid = threadIdx.x;
    const int p = tid & 3;      // quad member
    const int q = tid >> 2;     // quad id 0..63
    const int* tg = tags + (size_t)b * CRF_S;
    const float* mk = mask + (size_t)b * CRF_S;
    const float* emr = em + (size_t)b * CRF_S * CRF_T;

    // ---- tag-gather part ----
    float g_acc = 0.f;
#pragma unroll
    for (int k = 0; k < 4; ++k) {
        int t = tid + k * 256;
        int tagt = tg[t];
        float m = mk[t];
        g_acc += emr[(size_t)t * CRF_T + tagt] * m;
        if (t >= 1) g_acc += trans[tg[t - 1] * CRF_T + tagt] * m;
    }
    if (tid == 0) {
        g_acc += startT[tg[0]];
        g_acc += endT[tg[CRF_S - 1]] * mk[CRF_S - 1];
    }

    // ---- S2 part: quad q handles rows q, q+64, ... ; lane p cols 4p+16k ----
    float s2 = 0.f;
#pragma unroll 1
    for (int it = 0; it < 16; ++it) {
        const int r = it * 64 + q;
        const float* row = emr + (size_t)r * CRF_T;
        f32x4 sum4 = {0.f, 0.f, 0.f, 0.f};
#pragma unroll
        for (int k = 0; k < 8; ++k)
            sum4 += exp4(*(const f32x4*)(row + k * 16 + p * 4));
        float s = hsum4(sum4);
        s = dpp_add_xor1(s);
        s = dpp_add_xor2(s);
        if (p == 0) s2 += __logf(s) * mk[r];
    }

    float contrib = s2 - g_acc;
#pragma unroll
    for (int d = 1; d < 64; d <<= 1) contrib += __shfl_xor(contrib, d);
    __shared__ float r4[4];
    if ((tid & 63) == 0) r4[tid >> 6] = contrib;
    __syncthreads();
    if (tid == 0) {
        float tot = (r4[0] + r4[1]) + (r4[2] + r4[3]);
        atomicAdd(out, tot * (1.0f / CRF_B));
    }
}

// ---------------------------------------------------------------------------
// Kernel 2: scaled linear-domain forward recursion only.
// One block per batch, 128 threads (2 waves).
// Lane: p=tid&3 (row group of 32), q=tid>>2 (col quad, 4 cols j0=4q).
// E tile 32x4 in 128 VGPRs. Per step: 8 swizzled ds_read_b128 (conflict-free,
// 16-lane broadcast), 64 pk-FMA, quad DPP reduce (VALU), leader ds_write_b128,
// lgkm-only barrier. Rescale lazy every 4 steps (csum@t%4==2, rc@t%4==3 by
// leaders, applied @t%4==0). em exp'd one 4-group ahead (off-chain).
// ---------------------------------------------------------------------------
__global__ __launch_bounds__(128, 1) void crf_fwd_kernel(
    const float* __restrict__ em, const float* __restrict__ mask,
    const float* __restrict__ startT, const float* __restrict__ endT,
    const float* __restrict__ trans, float* __restrict__ out)
{
    const int b = blockIdx.x;
    const int tid = threadIdx.x;
    const int p = tid & 3;
    const int q = tid >> 2;      // 0..31
    const int j0 = q * 4;
    const bool leader = (p == 0);

    __shared__ __align__(16) float Abuf[2][CRF_T];
    __shared__ __align__(16) float partsA[32];
    __shared__ float red[4];
    __shared__ float lzsh;

    // E regs: EE[k][c][s] = exp(trans[i][j0+c]), i = p*32 + ((k+2p)&7)*4 + s.
    // The (k+2p)&7 phase makes the per-step 4-address ds_read_b128 hit 4
    // distinct bank quads (conflict-free).
    f32x4 EE[8][4];
#pragma unroll
    for (int k = 0; k < 8; ++k) {
        const int kp = (k + 2 * p) & 7;
#pragma unroll
        for (int s = 0; s < 4; ++s) {
            const int i = p * 32 + kp * 4 + s;
            f32x4 t4 = *(const f32x4*)&trans[i * CRF_T + j0];
            EE[k][0][s] = __expf(t4.x);
            EE[k][1][s] = __expf(t4.y);
            EE[k][2][s] = __expf(t4.z);
            EE[k][3][s] = __expf(t4.w);
        }
    }

    const float* emb = em + (size_t)b * CRF_S * CRF_T + j0;
    const float mlast = mask[(size_t)b * CRF_S + (CRF_S - 1)];

    float logZ = 0.f;   // leaders only
    float rc = 1.f;     // leaders only (others stay 1; their alpha is unused)

    // em pipeline: emv holds group g+1's raw em; eh[cur] in use, eh[nxt]
    // built this group.
    f32x4 emv[4], eh[2][4];
#pragma unroll
    for (int k = 0; k < 4; ++k) emv[k] = *(const f32x4*)(emb + (size_t)k * CRF_T);
#pragma unroll
    for (int k = 0; k < 4; ++k) eh[0][k] = exp4(emv[k]);
#pragma unroll
    for (int k = 0; k < 4; ++k) emv[k] = *(const f32x4*)(emb + (size_t)(4 + k) * CRF_T);

    auto STEP = [&](int t, int role, f32x4 ehv) {
        const int rb = (t & 1) ^ 1, wb = t & 1;

        if (role == 3 && leader) {
            // consume csum partials written at t-1 (t%4==2); rc used at t+1
            const f32x4* pa = (const f32x4*)partsA;
            f32x4 s8 = ((pa[0] + pa[1]) + (pa[2] + pa[3])) +
                       ((pa[4] + pa[5]) + (pa[6] + pa[7]));
            float c = hsum4(s8);
            rc = __builtin_amdgcn_rcpf(c);
            logZ += __logf(c);
        }

        // matvec partial: 32 rows x 4 cols
        const f32x4* Ab = (const f32x4*)&Abuf[rb][p * 32];
        f32x4 ac0 = {0.f, 0.f, 0.f, 0.f}, ac1 = ac0, ac2 = ac0, ac3 = ac0;
#pragma unroll
        for (int k = 0; k < 8; ++k) {
            f32x4 av = Ab[(k + 2 * p) & 7];
            ac0 = __builtin_elementwise_fma(av, EE[k][0], ac0);
            ac1 = __builtin_elementwise_fma(av, EE[k][1], ac1);
            ac2 = __builtin_elementwise_fma(av, EE[k][2], ac2);
            ac3 = __builtin_elementwise_fma(av, EE[k][3], ac3);
        }
        float d0 = hsum4(ac0), d1 = hsum4(ac1), d2 = hsum4(ac2), d3 = hsum4(ac3);
        // quad reduce via DPP (VALU pipe)
        d0 = dpp_add_xor2(dpp_add_xor1(d0));
        d1 = dpp_add_xor2(dpp_add_xor1(d1));
        d2 = dpp_add_xor2(dpp_add_xor1(d2));
        d3 = dpp_add_xor2(dpp_add_xor1(d3));

        float a0 = d0 * ehv.x, a1 = d1 * ehv.y, a2 = d2 * ehv.z, a3 = d3 * ehv.w;
        if (role == 0) { a0 *= rc; a1 *= rc; a2 *= rc; a3 *= rc; }
        if (leader) {
            f32x4 av = {a0, a1, a2, a3};
            *(f32x4*)&Abuf[wb][j0] = av;
            if (role == 2) partsA[q] = (a0 + a1) + (a2 + a3);
        }
        barrier_lds_only();
    };

    // ---- group 0: t=0 init + steps 1..3 ----
    {
        f32x4 s4 = *(const f32x4*)&startT[j0];
        if (leader) {
            f32x4 a;
            a.x = __expf(s4.x) * eh[0][0].x;
            a.y = __expf(s4.y) * eh[0][0].y;
            a.z = __expf(s4.z) * eh[0][0].z;
            a.w = __expf(s4.w) * eh[0][0].w;
            *(f32x4*)&Abuf[0][j0] = a;
        }
        barrier_lds_only();
        STEP(1, 1, eh[0][1]);
#pragma unroll
        for (int k = 0; k < 4; ++k) eh[1][k] = exp4(emv[k]);   // group 1
        STEP(2, 2, eh[0][2]);
#pragma unroll
        for (int k = 0; k < 4; ++k) emv[k] = *(const f32x4*)(emb + (size_t)(8 + k) * CRF_T); // group 2
        STEP(3, 3, eh[0][3]);
    }

    // ---- groups 1..255 ----
#pragma unroll 1
    for (int g = 1; g < 256; ++g) {
        const int t0 = 4 * g;
        const int cur = g & 1, nxt = cur ^ 1;
        STEP(t0 + 0, 0, eh[cur][0]);
        STEP(t0 + 1, 1, eh[cur][1]);
        if (g <= 254) {
#pragma unroll
            for (int k = 0; k < 4; ++k) eh[nxt][k] = exp4(emv[k]);  // group g+1
        }
        STEP(t0 + 2, 2, eh[cur][2]);
        if (g <= 253) {
#pragma unroll
            for (int k = 0; k < 4; ++k)
                emv[k] = *(const f32x4*)(emb + (size_t)(t0 + 8 + k) * CRF_T); // group g+2
        }
        STEP(t0 + 3, 3, eh[cur][3]);
    }

    // ---- finale: A~_1023 in Abuf[1]; logZ in leader lanes ----
    __syncthreads();
    if (tid == 0) lzsh = logZ;
    __syncthreads();
    const float lz = lzsh;

    float v = (__logf(Abuf[1][tid]) + lz) * mlast + endT[tid];
    float mx = v;
#pragma unroll
    for (int dd = 1; dd < 64; dd <<= 1) mx = fmaxf(mx, __shfl_xor(mx, dd));
    if ((tid & 63) == 0) red[tid >> 6] = mx;
    __syncthreads();
    mx = fmaxf(red[0], red[1]);
    float ex = __expf(v - mx);
#pragma unroll
    for (int dd = 1; dd < 64; dd <<= 1) ex += __shfl_xor(ex, dd);
    if ((tid & 63) == 0) red[2 + (tid >> 6)] = ex;
    __syncthreads();
    if (tid == 0) {
        float fwd = mx + __logf(red[2] + red[3]);
        atomicAdd(out, fwd * (1.0f / CRF_B));
    }
}

// ---------------------------------------------------------------------------
extern "C" void kernel_launch(void* const* d_in, const int* in_sizes, int n_in,
                              void* d_out, int out_size, void* d_ws, size_t ws_size,
                              hipStream_t stream)
{
    const float* em     = (const float*)d_in[0];
    const int*   tags   = (const int*)d_in[1];
    const float* mask   = (const float*)d_in[2];
    const float* startT = (const float*)d_in[3];
    const float* endT   = (const float*)d_in[4];
    const float* trans  = (const float*)d_in[5];
    float* out = (float*)d_out;

    hipMemsetAsync(out, 0, sizeof(float), stream);
    hipLaunchKernelGGL(crf_gold_kernel, dim3(CRF_B), dim3(256), 0, stream,
                       em, tags, mask, startT, endT, trans, out);
    hipLaunchKernelGGL(crf_fwd_kernel, dim3(CRF_B), dim3(128), 0, stream,
                       em, mask, startT, endT, trans, out);
}

// Round 5
// 597.979 us; speedup vs baseline: 1.4594x; 1.0625x over previous
//
#include <hip/hip_runtime.h>

#define CRF_B 256
#define CRF_S 1024
#define CRF_T 128

typedef __attribute__((ext_vector_type(4))) float f32x4;

// Barrier that waits only on LDS ops (lgkmcnt), NOT vmcnt: keeps global
// em-prefetch loads in flight across steps (__syncthreads drains vmcnt(0)).
__device__ __forceinline__ void barrier_lds_only() {
    __asm__ volatile("s_waitcnt lgkmcnt(0)\n\ts_barrier" ::: "memory");
}

// Cross-lane butterfly adds on the VALU pipe (DPP), no LDS/bpermute.
__device__ __forceinline__ float dpp_add_xor1(float x) {      // quad_perm [1,0,3,2]
    int y = __builtin_amdgcn_mov_dpp(__float_as_int(x), 0xB1, 0xF, 0xF, false);
    return x + __int_as_float(y);
}
__device__ __forceinline__ float dpp_add_xor2(float x) {      // quad_perm [2,3,0,1]
    int y = __builtin_amdgcn_mov_dpp(__float_as_int(x), 0x4E, 0xF, 0xF, false);
    return x + __int_as_float(y);
}
// After xor1+xor2 the value is quad-uniform, so ROW_HALF_MIRROR (lane^7 within
// 8) acts as xor4: combines the two quads of each 8-lane row group.
__device__ __forceinline__ float dpp_add_xor4u(float x) {     // ROW_HALF_MIRROR
    int y = __builtin_amdgcn_mov_dpp(__float_as_int(x), 0x141, 0xF, 0xF, false);
    return x + __int_as_float(y);
}

__device__ __forceinline__ f32x4 exp4(f32x4 v) {
    f32x4 r;
    r.x = __expf(v.x); r.y = __expf(v.y); r.z = __expf(v.z); r.w = __expf(v.w);
    return r;
}
__device__ __forceinline__ float hsum4(f32x4 v) {
    return (v.x + v.y) + (v.z + v.w);
}

// ---------------------------------------------------------------------------
// Kernel 1: tag-gather terms (negated) + S2 = sum_t m_t*log(sum_j exp(em_tj)).
// S2 is recursion-independent: it lives here (parallel, HBM-bound), keeping
// the serial fwd kernel's critical path free of it.
// ---------------------------------------------------------------------------
__global__ __launch_bounds__(256) void crf_gold_kernel(
    const float* __restrict__ em, const int* __restrict__ tags,
    const float* __restrict__ mask, const float* __restrict__ startT,
    const float* __restrict__ endT, const float* __restrict__ trans,
    float* __restrict__ out)
{
    const int b = blockIdx.x;
    const int tid = threadIdx.x;
    const int p = tid & 3;      // quad member
    const int q = tid >> 2;     // quad id 0..63
    const int* tg = tags + (size_t)b * CRF_S;
    const float* mk = mask + (size_t)b * CRF_S;
    const float* emr = em + (size_t)b * CRF_S * CRF_T;

    // ---- tag-gather part ----
    float g_acc = 0.f;
#pragma unroll
    for (int k = 0; k < 4; ++k) {
        int t = tid + k * 256;
        int tagt = tg[t];
        float m = mk[t];
        g_acc += emr[(size_t)t * CRF_T + tagt] * m;
        if (t >= 1) g_acc += trans[tg[t - 1] * CRF_T + tagt] * m;
    }
    if (tid == 0) {
        g_acc += startT[tg[0]];
        g_acc += endT[tg[CRF_S - 1]] * mk[CRF_S - 1];
    }

    // ---- S2 part: quad q handles rows q, q+64, ... ; lane p cols 4p+16k ----
    float s2 = 0.f;
#pragma unroll 1
    for (int it = 0; it < 16; ++it) {
        const int r = it * 64 + q;
        const float* row = emr + (size_t)r * CRF_T;
        f32x4 sum4 = {0.f, 0.f, 0.f, 0.f};
#pragma unroll
        for (int k = 0; k < 8; ++k)
            sum4 += exp4(*(const f32x4*)(row + k * 16 + p * 4));
        float s = hsum4(sum4);
        s = dpp_add_xor1(s);
        s = dpp_add_xor2(s);
        if (p == 0) s2 += __logf(s) * mk[r];
    }

    float contrib = s2 - g_acc;
#pragma unroll
    for (int d = 1; d < 64; d <<= 1) contrib += __shfl_xor(contrib, d);
    __shared__ float r4[4];
    if ((tid & 63) == 0) r4[tid >> 6] = contrib;
    __syncthreads();
    if (tid == 0) {
        float tot = (r4[0] + r4[1]) + (r4[2] + r4[3]);
        atomicAdd(out, tot * (1.0f / CRF_B));
    }
}

// ---------------------------------------------------------------------------
// Kernel 2: scaled linear-domain forward recursion only.
// One block per batch, 256 threads (4 waves -> 4 SIMDs).
// Lane mapping: r = tid&7 (row group of 16, lane bits 0-2), cq = tid>>3
// (col quad 0..31, 4 cols j0=4*cq). E tile 16x4 = 64 VGPRs/thread (NO spill
// -- R4's 128-reg tile spilled to AGPRs and paid ~128 moves/step).
// Per step: 4 swizzled ds_read_b128 (8-lane broadcast, only free 2-way
// aliasing), 16 f32x4 FMAs, 3 DPP adds (VALU, no LDS crossbar), leader
// ds_write_b128, lgkm-only barrier. Rescale lazy every 4 steps.
// ---------------------------------------------------------------------------
__global__ __launch_bounds__(256, 1) void crf_fwd_kernel(
    const float* __restrict__ em, const float* __restrict__ mask,
    const float* __restrict__ startT, const float* __restrict__ endT,
    const float* __restrict__ trans, float* __restrict__ out)
{
    const int b = blockIdx.x;
    const int tid = threadIdx.x;
    const int r = tid & 7;       // row group: rows r*16 .. r*16+15
    const int cq = tid >> 3;     // 0..31
    const int j0 = cq * 4;
    const bool leader = (r == 0);

    __shared__ __align__(16) float Abuf[2][CRF_T];
    __shared__ __align__(16) float partsA[32];
    __shared__ float red[8];
    __shared__ float lzsh;

    // k-swizzle: thread's 4 b128 reads at float-idx r*16 + ((k+r)&3)*4.
    int kidx[4];
#pragma unroll
    for (int k = 0; k < 4; ++k) kidx[k] = (k + r) & 3;

    // EE[k][c][s] = exp(trans[i][j0+c]), i = r*16 + kidx[k]*4 + s  (64 VGPRs)
    f32x4 EE[4][4];
#pragma unroll
    for (int k = 0; k < 4; ++k) {
#pragma unroll
        for (int s = 0; s < 4; ++s) {
            const int i = r * 16 + kidx[k] * 4 + s;
            f32x4 t4 = *(const f32x4*)&trans[i * CRF_T + j0];
            EE[k][0][s] = __expf(t4.x);
            EE[k][1][s] = __expf(t4.y);
            EE[k][2][s] = __expf(t4.z);
            EE[k][3][s] = __expf(t4.w);
        }
    }

    const float* emb = em + (size_t)b * CRF_S * CRF_T + j0;
    const float mlast = mask[(size_t)b * CRF_S + (CRF_S - 1)];

    float logZ = 0.f;   // leaders only
    float rc = 1.f;     // leaders only (non-leader alpha is never written)

    // em pipeline: eh[cur] in use, eh[nxt] built this group; emv = group g+2.
    f32x4 emv[4], eh[2][4];
#pragma unroll
    for (int k = 0; k < 4; ++k) emv[k] = *(const f32x4*)(emb + (size_t)k * CRF_T);
#pragma unroll
    for (int k = 0; k < 4; ++k) eh[0][k] = exp4(emv[k]);
#pragma unroll
    for (int k = 0; k < 4; ++k) emv[k] = *(const f32x4*)(emb + (size_t)(4 + k) * CRF_T);

    auto STEP = [&](int t, int role, f32x4 ehv) {
        const int rb = (t & 1) ^ 1, wb = t & 1;

        // t==1023's rescale is never applied -> must NOT enter logZ (R4 bug).
        if (role == 3 && leader && t < 1023) {
            const f32x4* pa = (const f32x4*)partsA;   // csum written at t-1
            f32x4 s8 = ((pa[0] + pa[1]) + (pa[2] + pa[3])) +
                       ((pa[4] + pa[5]) + (pa[6] + pa[7]));
            float c = hsum4(s8);
            rc = __builtin_amdgcn_rcpf(c);
            logZ += __logf(c);
        }

        const f32x4* Ab = (const f32x4*)&Abuf[rb][r * 16];
        f32x4 ac0 = {0.f, 0.f, 0.f, 0.f}, ac1 = ac0, ac2 = ac0, ac3 = ac0;
#pragma unroll
        for (int k = 0; k < 4; ++k) {
            f32x4 av = Ab[kidx[k]];
            ac0 = __builtin_elementwise_fma(av, EE[k][0], ac0);
            ac1 = __builtin_elementwise_fma(av, EE[k][1], ac1);
            ac2 = __builtin_elementwise_fma(av, EE[k][2], ac2);
            ac3 = __builtin_elementwise_fma(av, EE[k][3], ac3);
        }
        float d0 = hsum4(ac0), d1 = hsum4(ac1), d2 = hsum4(ac2), d3 = hsum4(ac3);
        d0 = dpp_add_xor4u(dpp_add_xor2(dpp_add_xor1(d0)));
        d1 = dpp_add_xor4u(dpp_add_xor2(dpp_add_xor1(d1)));
        d2 = dpp_add_xor4u(dpp_add_xor2(dpp_add_xor1(d2)));
        d3 = dpp_add_xor4u(dpp_add_xor2(dpp_add_xor1(d3)));

        float a0 = d0 * ehv.x, a1 = d1 * ehv.y, a2 = d2 * ehv.z, a3 = d3 * ehv.w;
        if (role == 0) { a0 *= rc; a1 *= rc; a2 *= rc; a3 *= rc; }
        if (leader) {
            f32x4 av = {a0, a1, a2, a3};
            *(f32x4*)&Abuf[wb][j0] = av;
            if (role == 2) partsA[cq] = (a0 + a1) + (a2 + a3);
        }
        barrier_lds_only();
    };

    // ---- group 0: t=0 init + steps 1..3 ----
    {
        f32x4 s4 = *(const f32x4*)&startT[j0];
        if (leader) {
            f32x4 a;
            a.x = __expf(s4.x) * eh[0][0].x;
            a.y = __expf(s4.y) * eh[0][0].y;
            a.z = __expf(s4.z) * eh[0][0].z;
            a.w = __expf(s4.w) * eh[0][0].w;
            *(f32x4*)&Abuf[0][j0] = a;
        }
        barrier_lds_only();
        STEP(1, 1, eh[0][1]);
#pragma unroll
        for (int k = 0; k < 4; ++k) eh[1][k] = exp4(emv[k]);   // group 1
        STEP(2, 2, eh[0][2]);
#pragma unroll
        for (int k = 0; k < 4; ++k) emv[k] = *(const f32x4*)(emb + (size_t)(8 + k) * CRF_T); // group 2
        STEP(3, 3, eh[0][3]);
    }

    // ---- groups 1..255 ----
#pragma unroll 1
    for (int g = 1; g < 256; ++g) {
        const int t0 = 4 * g;
        const int cur = g & 1, nxt = cur ^ 1;
        STEP(t0 + 0, 0, eh[cur][0]);
        STEP(t0 + 1, 1, eh[cur][1]);
        if (g <= 254) {
#pragma unroll
            for (int k = 0; k < 4; ++k) eh[nxt][k] = exp4(emv[k]);  // group g+1
        }
        STEP(t0 + 2, 2, eh[cur][2]);
        if (g <= 253) {
#pragma unroll
            for (int k = 0; k < 4; ++k)
                emv[k] = *(const f32x4*)(emb + (size_t)(t0 + 8 + k) * CRF_T); // group g+2
        }
        STEP(t0 + 3, 3, eh[cur][3]);
    }

    // ---- finale: A~_1023 in Abuf[1]; logZ in leader lanes ----
    __syncthreads();
    if (tid == 0) lzsh = logZ;
    __syncthreads();
    const float lz = lzsh;

    float v = -3.0e38f;
    if (tid < 128)
        v = (__logf(Abuf[1][tid]) + lz) * mlast + endT[tid];
    float mx = v;
#pragma unroll
    for (int dd = 1; dd < 64; dd <<= 1) mx = fmaxf(mx, __shfl_xor(mx, dd));
    if ((tid & 63) == 0) red[tid >> 6] = mx;
    __syncthreads();
    mx = fmaxf(fmaxf(red[0], red[1]), fmaxf(red[2], red[3]));
    float ex = (tid < 128) ? __expf(v - mx) : 0.f;
#pragma unroll
    for (int dd = 1; dd < 64; dd <<= 1) ex += __shfl_xor(ex, dd);
    if ((tid & 63) == 0) red[4 + (tid >> 6)] = ex;
    __syncthreads();
    if (tid == 0) {
        float sm = (red[4] + red[5]) + (red[6] + red[7]);
        float fwd = mx + __logf(sm);
        atomicAdd(out, fwd * (1.0f / CRF_B));
    }
}

// ---------------------------------------------------------------------------
extern "C" void kernel_launch(void* const* d_in, const int* in_sizes, int n_in,
                              void* d_out, int out_size, void* d_ws, size_t ws_size,
                              hipStream_t stream)
{
    const float* em     = (const float*)d_in[0];
    const int*   tags   = (const int*)d_in[1];
    const float* mask   = (const float*)d_in[2];
    const float* startT = (const float*)d_in[3];
    const float* endT   = (const float*)d_in[4];
    const float* trans  = (const float*)d_in[5];
    float* out = (float*)d_out;

    hipMemsetAsync(out, 0, sizeof(float), stream);
    hipLaunchKernelGGL(crf_gold_kernel, dim3(CRF_B), dim3(256), 0, stream,
                       em, tags, mask, startT, endT, trans, out);
    hipLaunchKernelGGL(crf_fwd_kernel, dim3(CRF_B), dim3(256), 0, stream,
                       em, mask, startT, endT, trans, out);
}